// Round 4
// baseline (250.875 us; speedup 1.0000x reference)
//
#include <hip/hip_runtime.h>
#include <math.h>

#define N_NODES 50000
#define N_EDGES 800000
#define IN_DIM 32
#define HIDDEN 64
#define Z_DIM 32
#define SCAN_B 256
#define NB_SCAN ((N_NODES + SCAN_B - 1) / SCAN_B)   // 196
#define N_XCD 8
#define NPX ((N_NODES + N_XCD - 1) / N_XCD)         // 6250 nodes per XCD range
#define SLICE 2048
#define N_SLICE ((N_EDGES + SLICE - 1) / SLICE)     // 391
#define SCAT_B (N_SLICE * N_XCD)                    // 3128 hist blocks
#define FB 2048                                     // 8192 waves for node kernels
#define CPAD 16                                     // cnt stride: 1 line/node

// bf16 (stored as ushort) <-> f32 helpers, RNE
__device__ __forceinline__ unsigned short f2bf(float f) {
    unsigned int u = __float_as_uint(f);
    u += 0x7fffu + ((u >> 16) & 1u);
    return (unsigned short)(u >> 16);
}

// wave-local edge dtype detect: int64 LE values < 2^31 have all-zero odd words.
__device__ __forceinline__ int detect64(const int* raw) {
    int lane = threadIdx.x & 63;
    int odd = raw[2 * lane + 1];
    unsigned long long b = __ballot(odd != 0);
    return (b == 0ULL) ? 1 : 0;
}

// 8 bf16 (packed in uint4) FMA into acc[8]
__device__ __forceinline__ void fma8(float w, uint4 f, float acc[8]) {
    acc[0] = fmaf(w, __uint_as_float(f.x << 16),         acc[0]);
    acc[1] = fmaf(w, __uint_as_float(f.x & 0xffff0000u), acc[1]);
    acc[2] = fmaf(w, __uint_as_float(f.y << 16),         acc[2]);
    acc[3] = fmaf(w, __uint_as_float(f.y & 0xffff0000u), acc[3]);
    acc[4] = fmaf(w, __uint_as_float(f.z << 16),         acc[4]);
    acc[5] = fmaf(w, __uint_as_float(f.z & 0xffff0000u), acc[5]);
    acc[6] = fmaf(w, __uint_as_float(f.w << 16),         acc[6]);
    acc[7] = fmaf(w, __uint_as_float(f.w & 0xffff0000u), acc[7]);
}
__device__ __forceinline__ void mul8(float w, uint4 f, float acc[8]) {
    acc[0] = w * __uint_as_float(f.x << 16);
    acc[1] = w * __uint_as_float(f.x & 0xffff0000u);
    acc[2] = w * __uint_as_float(f.y << 16);
    acc[3] = w * __uint_as_float(f.y & 0xffff0000u);
    acc[4] = w * __uint_as_float(f.z << 16);
    acc[5] = w * __uint_as_float(f.z & 0xffff0000u);
    acc[6] = w * __uint_as_float(f.w << 16);
    acc[7] = w * __uint_as_float(f.w & 0xffff0000u);
}

// ---------------------------------------------------------------------------
// prep_a: pure streaming. x->bf16 convert; edge compaction to ushort2 (node
// ids < 2^16); cnt zeroing folded in (saves the memset dispatch).
__global__ void prep_a_kernel(const float* __restrict__ x, unsigned short* __restrict__ xb,
                              const void* __restrict__ raw, ushort2* __restrict__ ep0,
                              int* __restrict__ cnt) {
    int is64 = detect64((const int*)raw);
    int i = blockIdx.x * 256 + threadIdx.x;
    if (i < N_NODES * IN_DIM) xb[i] = f2bf(x[i]);
    if (i < N_NODES * CPAD) cnt[i] = 0;
    if (i < N_EDGES) {
        int s, d;
        if (is64) {
            s = (int)((const long long*)raw)[i];
            d = (int)((const long long*)raw)[N_EDGES + i];
        } else {
            s = ((const int*)raw)[i];
            d = ((const int*)raw)[N_EDGES + i];
        }
        ep0[i] = make_ushort2((unsigned short)s, (unsigned short)d);
    }
}

// ---------------------------------------------------------------------------
// hist: XCD-partitioned degree count + per-edge rank capture. xcd = b%8 owns
// dst range -> atomics local to one XCD's L2. cnt padded 1 line/node. The
// atomic's return value is the edge's within-node rank.
__global__ __launch_bounds__(256) void hist_kernel(const ushort2* __restrict__ ep0,
                                                   int* __restrict__ cnt,
                                                   unsigned short* __restrict__ rank) {
    int xcd = blockIdx.x % N_XCD;
    int sl  = blockIdx.x / N_XCD;
    int lo  = xcd * NPX, hi = lo + NPX;
    int base = sl * SLICE;
#pragma unroll
    for (int j = 0; j < SLICE / 256; j++) {
        int e = base + j * 256 + threadIdx.x;
        if (e < N_EDGES) {
            int d = ep0[e].y;
            if (d >= lo && d < hi)
                rank[e] = (unsigned short)atomicAdd(&cnt[(size_t)d * CPAD], 1);
        }
    }
}

// ---------------------------------------------------------------------------
// scan1: block-local exclusive scan of cnt (padded) -> pre, block sums, dinv.
// Global offsets are applied by consumers via an LDS scan of bsum (no scan23).
__global__ void scan1_kernel(const int* __restrict__ cnt, int* __restrict__ pre,
                             int* __restrict__ bsum, float* __restrict__ dinv) {
    __shared__ int s[SCAN_B];
    int t = threadIdx.x;
    int g = blockIdx.x * SCAN_B + t;
    int v = (g < N_NODES) ? cnt[(size_t)g * CPAD] : 0;
    if (g < N_NODES) dinv[g] = rsqrtf((float)(v + 1));   // +1 self loop
    s[t] = v;
    __syncthreads();
    for (int o = 1; o < SCAN_B; o <<= 1) {
        int add = (t >= o) ? s[t - o] : 0;
        __syncthreads();
        s[t] += add;
        __syncthreads();
    }
    if (g < N_NODES) pre[g] = s[t] - v;
    if (t == SCAN_B - 1) bsum[blockIdx.x] = s[t];
}

// Block-start prologue: redundant LDS exclusive-scan of the 196 bsums.
// After this, rowptr(v) = pre[v] + sx[v>>8].
#define BSUM_SCAN_PROLOGUE(bsum, sb, sx)                                    \
    {                                                                       \
        int t_ = threadIdx.x;                                               \
        int bv_ = (t_ < NB_SCAN) ? bsum[t_] : 0;                            \
        sb[t_] = bv_;                                                       \
        __syncthreads();                                                    \
        for (int o_ = 1; o_ < 256; o_ <<= 1) {                              \
            int a_ = (t_ >= o_) ? sb[t_ - o_] : 0;                          \
            __syncthreads();                                                \
            sb[t_] += a_;                                                   \
            __syncthreads();                                                \
        }                                                                   \
        sx[t_] = sb[t_] - bv_;                                              \
        __syncthreads();                                                    \
    }

// ---------------------------------------------------------------------------
// Deterministic scatter: single pass, no atomics. Slot = rowptr[dst] + rank.
__global__ __launch_bounds__(256) void scatter_kernel(
        const ushort2* __restrict__ ep0, const unsigned short* __restrict__ rank,
        const int* __restrict__ pre, const int* __restrict__ bsum,
        const float* __restrict__ dinv, int2* __restrict__ ep) {
    __shared__ int sb[256];
    __shared__ int sx[256];
    BSUM_SCAN_PROLOGUE(bsum, sb, sx)
    int base = blockIdx.x * SLICE;
#pragma unroll
    for (int j = 0; j < SLICE / 256; j++) {
        int e = base + j * 256 + threadIdx.x;
        if (e < N_EDGES) {
            ushort2 sd = ep0[e];
            int d = sd.y;
            int p = pre[d] + sx[d >> 8] + (int)rank[e];
            int s = sd.x;
            ep[p] = make_int2(s, __float_as_int(dinv[s]));
        }
    }
}

// ---------------------------------------------------------------------------
// 64-wide aggregation. Edge batch staged once into the wave's LDS slot, then
// one ds_read_b64 per 8-edge group. Feature gathers are uint4: 8 lanes x 16B
// cover one 128B row -> 8 edges per load instruction. Masked slots hold
// (s=0,w=0): row-0 gather is an L1 broadcast hit, FMA contributes 0.
__device__ __forceinline__ void agg64(int e0, int e1, int2 pr,
                                      const int2* __restrict__ ep,
                                      const uint4* __restrict__ g4,
                                      int2* eb, int lane, int gsel, int c,
                                      float acc[8]) {
    for (int b0 = e0; b0 < e1; b0 += 64) {
        int cnt = e1 - b0; cnt = cnt > 64 ? 64 : cnt;        // uniform
        eb[lane] = pr;                                       // stage batch
        for (int j = 0; j < cnt; j += 16) {
            int2 ew0 = eb[j + gsel];                         // gsel in 0..7
            int2 ew1 = eb[j + 8 + gsel];
            uint4 f0 = g4[(size_t)ew0.x * 8 + c];
            uint4 f1 = g4[(size_t)ew1.x * 8 + c];
            fma8(__int_as_float(ew0.y), f0, acc);
            fma8(__int_as_float(ew1.y), f1, acc);
        }
        if (b0 + 64 < e1) {                                  // rare extra batch
            pr = make_int2(0, 0);
            int idx = b0 + 64 + lane;
            if (idx < e1) pr = ep[idx];
        }
    }
}

// 32-wide aggregation: 4 lanes x 16B cover one 64B row -> 16 edges per load.
__device__ __forceinline__ void agg32(int e0, int e1, int2 pr,
                                      const int2* __restrict__ ep,
                                      const uint4* __restrict__ x4,
                                      int2* eb, int lane, int gsel, int c,
                                      float acc[8]) {
    for (int b0 = e0; b0 < e1; b0 += 64) {
        int cnt = e1 - b0; cnt = cnt > 64 ? 64 : cnt;
        eb[lane] = pr;
        for (int j = 0; j < cnt; j += 32) {
            int2 ew0 = eb[j + gsel];                         // gsel in 0..15
            int2 ew1 = eb[j + 16 + gsel];
            uint4 f0 = x4[(size_t)ew0.x * 4 + c];
            uint4 f1 = x4[(size_t)ew1.x * 4 + c];
            fma8(__int_as_float(ew0.y), f0, acc);
            fma8(__int_as_float(ew1.y), f1, acc);
        }
        if (b0 + 64 < e1) {
            pr = make_int2(0, 0);
            int idx = b0 + 64 + lane;
            if (idx < e1) pr = ep[idx];
        }
    }
}

// ---------------------------------------------------------------------------
// Fused layer 1: q = normAgg(xb) [32-wide, f32], out = relu(q @ W1 + b1).
__global__ __launch_bounds__(256, 4) void fused_layer32_kernel(
        const int* __restrict__ pre, const int* __restrict__ bsum,
        const int2* __restrict__ ep, const float* __restrict__ dinv,
        const unsigned short* __restrict__ xb,
        const float* __restrict__ W1, const float* __restrict__ b1,
        unsigned short* __restrict__ out) {
    __shared__ int sb[256];
    __shared__ int sx[256];
    __shared__ int2 ebuf[4][64];
    __shared__ float sq[4][32];
    BSUM_SCAN_PROLOGUE(bsum, sb, sx)
    int lane = threadIdx.x & 63;
    int wav  = threadIdx.x >> 6;
    int gsel = lane >> 2;                                    // 16 groups
    int c    = lane & 3;                                     // 4 x uint4 = 64B row
    const uint4* x4 = (const uint4*)xb;
    int2* eb = &ebuf[wav][0];
    float wcol[IN_DIM];
#pragma unroll
    for (int k = 0; k < IN_DIM; k++) wcol[k] = W1[k * 64 + lane];
    float bb = b1[lane];
    int wid = __builtin_amdgcn_readfirstlane((int)((blockIdx.x * blockDim.x + threadIdx.x) >> 6));
    int nw  = (gridDim.x * blockDim.x) >> 6;
    int v = wid;
    if (v >= N_NODES) return;
    int e0 = pre[v] + sx[v >> 8];
    int e1 = (v + 1 < N_NODES) ? pre[v + 1] + sx[(v + 1) >> 8] : N_EDGES;
    float dv = dinv[v];
    uint4 hv = x4[(size_t)v * 4 + c];
    int2 pr = make_int2(0, 0);
    if (lane < e1 - e0) pr = ep[e0 + lane];                  // exec-masked load
    while (v < N_NODES) {
        int vn = v + nw;
        int e0n = 0, e1n = 0;
        float dvn = 0.0f;
        uint4 hvn = make_uint4(0, 0, 0, 0);
        int2 prn = make_int2(0, 0);
        if (vn < N_NODES) {                                  // prefetch next node
            e0n = pre[vn] + sx[vn >> 8];
            e1n = (vn + 1 < N_NODES) ? pre[vn + 1] + sx[(vn + 1) >> 8] : N_EDGES;
            dvn = dinv[vn];
            hvn = x4[(size_t)vn * 4 + c];
            if (lane < e1n - e0n) prn = ep[e0n + lane];
        }
        float sv = (gsel == 0) ? dv : 0.0f;                  // self term once
        float acc[8];
        mul8(sv, hv, acc);
        agg32(e0, e1, pr, ep, x4, eb, lane, gsel, c, acc);
#pragma unroll
        for (int i = 0; i < 8; i++) {
            acc[i] += __shfl_xor(acc[i], 4);
            acc[i] += __shfl_xor(acc[i], 8);
            acc[i] += __shfl_xor(acc[i], 16);
            acc[i] += __shfl_xor(acc[i], 32);
        }
        if (lane < 4) {
            float4* qd = (float4*)(&sq[wav][lane * 8]);
            qd[0] = make_float4(dv * acc[0], dv * acc[1], dv * acc[2], dv * acc[3]);
            qd[1] = make_float4(dv * acc[4], dv * acc[5], dv * acc[6], dv * acc[7]);
        }
        float o = bb;
        const float4* q4 = (const float4*)(&sq[wav][0]);
#pragma unroll
        for (int k = 0; k < IN_DIM / 4; k++) {
            float4 tq = q4[k];
            o = fmaf(tq.x, wcol[4 * k + 0], o);
            o = fmaf(tq.y, wcol[4 * k + 1], o);
            o = fmaf(tq.z, wcol[4 * k + 2], o);
            o = fmaf(tq.w, wcol[4 * k + 3], o);
        }
        out[(size_t)v * 64 + lane] = f2bf(fmaxf(o, 0.0f));
        v = vn; e0 = e0n; e1 = e1n; dv = dvn; hv = hvn; pr = prn;
    }
}

// Fused layer 2: q = normAgg(g) [64-wide, f32], out = relu(q @ W + b).
__global__ __launch_bounds__(256, 4) void fused_layer64_kernel(
        const int* __restrict__ pre, const int* __restrict__ bsum,
        const int2* __restrict__ ep, const float* __restrict__ dinv,
        const unsigned short* __restrict__ g,
        const float* __restrict__ W, const float* __restrict__ bias,
        unsigned short* __restrict__ out) {
    __shared__ int sb[256];
    __shared__ int sx[256];
    __shared__ int2 ebuf[4][64];
    __shared__ float sq[4][64];
    BSUM_SCAN_PROLOGUE(bsum, sb, sx)
    int lane = threadIdx.x & 63;
    int wav  = threadIdx.x >> 6;
    int gsel = lane >> 3;                                    // 8 groups
    int c    = lane & 7;                                     // 8 x uint4 = 128B row
    const uint4* g4 = (const uint4*)g;
    int2* eb = &ebuf[wav][0];
    float wcol[HIDDEN];
#pragma unroll
    for (int k = 0; k < HIDDEN; k++) wcol[k] = W[k * 64 + lane];
    float bb = bias[lane];
    int wid = __builtin_amdgcn_readfirstlane((int)((blockIdx.x * blockDim.x + threadIdx.x) >> 6));
    int nw  = (gridDim.x * blockDim.x) >> 6;
    int v = wid;
    if (v >= N_NODES) return;
    int e0 = pre[v] + sx[v >> 8];
    int e1 = (v + 1 < N_NODES) ? pre[v + 1] + sx[(v + 1) >> 8] : N_EDGES;
    float dv = dinv[v];
    uint4 hv = g4[(size_t)v * 8 + c];
    int2 pr = make_int2(0, 0);
    if (lane < e1 - e0) pr = ep[e0 + lane];
    while (v < N_NODES) {
        int vn = v + nw;
        int e0n = 0, e1n = 0;
        float dvn = 0.0f;
        uint4 hvn = make_uint4(0, 0, 0, 0);
        int2 prn = make_int2(0, 0);
        if (vn < N_NODES) {
            e0n = pre[vn] + sx[vn >> 8];
            e1n = (vn + 1 < N_NODES) ? pre[vn + 1] + sx[(vn + 1) >> 8] : N_EDGES;
            dvn = dinv[vn];
            hvn = g4[(size_t)vn * 8 + c];
            if (lane < e1n - e0n) prn = ep[e0n + lane];
        }
        float sv = (gsel == 0) ? dv : 0.0f;
        float acc[8];
        mul8(sv, hv, acc);
        agg64(e0, e1, pr, ep, g4, eb, lane, gsel, c, acc);
#pragma unroll
        for (int i = 0; i < 8; i++) {
            acc[i] += __shfl_xor(acc[i], 8);
            acc[i] += __shfl_xor(acc[i], 16);
            acc[i] += __shfl_xor(acc[i], 32);
        }
        if (lane < 8) {
            float4* qd = (float4*)(&sq[wav][lane * 8]);
            qd[0] = make_float4(dv * acc[0], dv * acc[1], dv * acc[2], dv * acc[3]);
            qd[1] = make_float4(dv * acc[4], dv * acc[5], dv * acc[6], dv * acc[7]);
        }
        float o = bb;
        const float4* q4 = (const float4*)(&sq[wav][0]);
#pragma unroll
        for (int k = 0; k < HIDDEN / 4; k++) {
            float4 tq = q4[k];
            o = fmaf(tq.x, wcol[4 * k + 0], o);
            o = fmaf(tq.y, wcol[4 * k + 1], o);
            o = fmaf(tq.z, wcol[4 * k + 2], o);
            o = fmaf(tq.w, wcol[4 * k + 3], o);
        }
        out[(size_t)v * 64 + lane] = f2bf(fmaxf(o, 0.0f));
        v = vn; e0 = e0n; e1 = e1n; dv = dvn; hv = hvn; pr = prn;
    }
}

// Fused heads: q = normAgg(h2); mu = q@Wmu+bmu (lanes<32), lv = q@Wlv+blv
// (lanes>=32); z = mu + exp(.5 lv) * eps. d_out = [z | mu | lv] fp32.
__global__ __launch_bounds__(256, 4) void fused_head_kernel(
        const int* __restrict__ pre, const int* __restrict__ bsum,
        const int2* __restrict__ ep, const float* __restrict__ dinv,
        const unsigned short* __restrict__ g,
        const float* __restrict__ Wmu, const float* __restrict__ Wlv,
        const float* __restrict__ bmu, const float* __restrict__ blv,
        const float* __restrict__ eps, float* __restrict__ outz) {
    __shared__ int sb[256];
    __shared__ int sx[256];
    __shared__ int2 ebuf[4][64];
    __shared__ float sq[4][64];
    BSUM_SCAN_PROLOGUE(bsum, sb, sx)
    int lane = threadIdx.x & 63;
    int wav  = threadIdx.x >> 6;
    int gsel = lane >> 3;
    int c    = lane & 7;
    int f = lane & 31;
    bool hi = lane >= 32;
    const uint4* g4 = (const uint4*)g;
    int2* eb = &ebuf[wav][0];
    float wcol[HIDDEN];
#pragma unroll
    for (int k = 0; k < HIDDEN; k++)
        wcol[k] = hi ? Wlv[k * 32 + f] : Wmu[k * 32 + f];
    float bb = hi ? blv[f] : bmu[f];
    float* z  = outz;
    float* mu = outz + (size_t)N_NODES * Z_DIM;
    float* lv = outz + 2 * (size_t)N_NODES * Z_DIM;
    int wid = __builtin_amdgcn_readfirstlane((int)((blockIdx.x * blockDim.x + threadIdx.x) >> 6));
    int nw  = (gridDim.x * blockDim.x) >> 6;
    int v = wid;
    if (v >= N_NODES) return;
    int e0 = pre[v] + sx[v >> 8];
    int e1 = (v + 1 < N_NODES) ? pre[v + 1] + sx[(v + 1) >> 8] : N_EDGES;
    float dv = dinv[v];
    uint4 hv = g4[(size_t)v * 8 + c];
    int2 pr = make_int2(0, 0);
    if (lane < e1 - e0) pr = ep[e0 + lane];
    while (v < N_NODES) {
        int vn = v + nw;
        int e0n = 0, e1n = 0;
        float dvn = 0.0f;
        uint4 hvn = make_uint4(0, 0, 0, 0);
        int2 prn = make_int2(0, 0);
        if (vn < N_NODES) {
            e0n = pre[vn] + sx[vn >> 8];
            e1n = (vn + 1 < N_NODES) ? pre[vn + 1] + sx[(vn + 1) >> 8] : N_EDGES;
            dvn = dinv[vn];
            hvn = g4[(size_t)vn * 8 + c];
            if (lane < e1n - e0n) prn = ep[e0n + lane];
        }
        float sv = (gsel == 0) ? dv : 0.0f;
        float acc[8];
        mul8(sv, hv, acc);
        agg64(e0, e1, pr, ep, g4, eb, lane, gsel, c, acc);
#pragma unroll
        for (int i = 0; i < 8; i++) {
            acc[i] += __shfl_xor(acc[i], 8);
            acc[i] += __shfl_xor(acc[i], 16);
            acc[i] += __shfl_xor(acc[i], 32);
        }
        if (lane < 8) {
            float4* qd = (float4*)(&sq[wav][lane * 8]);
            qd[0] = make_float4(dv * acc[0], dv * acc[1], dv * acc[2], dv * acc[3]);
            qd[1] = make_float4(dv * acc[4], dv * acc[5], dv * acc[6], dv * acc[7]);
        }
        float m = bb;
        const float4* q4 = (const float4*)(&sq[wav][0]);
#pragma unroll
        for (int k = 0; k < HIDDEN / 4; k++) {
            float4 tq = q4[k];
            m = fmaf(tq.x, wcol[4 * k + 0], m);
            m = fmaf(tq.y, wcol[4 * k + 1], m);
            m = fmaf(tq.z, wcol[4 * k + 2], m);
            m = fmaf(tq.w, wcol[4 * k + 3], m);
        }
        float ev = eps[(size_t)v * Z_DIM + f];
        float t  = expf(0.5f * m) * ev;
        float tlo = __shfl(t, lane | 32);
        size_t o = (size_t)v * Z_DIM + f;
        if (!hi) { mu[o] = m; z[o] = m + tlo; }
        else     { lv[o] = m; }
        v = vn; e0 = e0n; e1 = e1n; dv = dvn; hv = hvn; pr = prn;
    }
}

// ---------------------------------------------------------------------------
extern "C" void kernel_launch(void* const* d_in, const int* in_sizes, int n_in,
                              void* d_out, int out_size, void* d_ws, size_t ws_size,
                              hipStream_t stream) {
    const float* x   = (const float*)d_in[0];
    const void*  ei  = d_in[1];
    const float* W1  = (const float*)d_in[2];
    const float* b1  = (const float*)d_in[3];
    const float* W2  = (const float*)d_in[4];
    const float* b2  = (const float*)d_in[5];
    const float* Wmu = (const float*)d_in[6];
    const float* bmu = (const float*)d_in[7];
    const float* Wlv = (const float*)d_in[8];
    const float* blv = (const float*)d_in[9];
    const float* eps = (const float*)d_in[10];
    float* out = (float*)d_out;
    (void)in_sizes; (void)n_in; (void)out_size; (void)ws_size;

    char* ws = (char*)d_ws;
    size_t off = 0;
    auto alloc = [&](size_t bytes) -> void* {
        void* p = ws + off;
        off += (bytes + 255) & ~(size_t)255;
        return p;
    };
    int2*           ep     = (int2*)alloc(sizeof(int2) * N_EDGES);       // 6.4 MB
    ushort2*        ep0    = (ushort2*)alloc(sizeof(ushort2) * N_EDGES); // 3.2 MB
    unsigned short* rank   = (unsigned short*)alloc(sizeof(short) * N_EDGES);  // 1.6 MB
    int*            pre    = (int*)alloc(sizeof(int) * (N_NODES + 1));
    int*            cnt    = (int*)alloc(sizeof(int) * (size_t)N_NODES * CPAD); // 3.2 MB
    float*          dinv   = (float*)alloc(sizeof(float) * N_NODES);
    int*            bsum   = (int*)alloc(sizeof(int) * 256);
    unsigned short* xb     = (unsigned short*)alloc(sizeof(short) * (size_t)N_NODES * IN_DIM);  // 3.2 MB
    unsigned short* G      = (unsigned short*)alloc(sizeof(short) * (size_t)N_NODES * HIDDEN);  // 6.4 MB
    unsigned short* H      = (unsigned short*)alloc(sizeof(short) * (size_t)N_NODES * HIDDEN);  // 6.4 MB

    prep_a_kernel<<<(N_NODES * IN_DIM + 255) / 256, 256, 0, stream>>>(x, xb, ei, ep0, cnt);
    hist_kernel<<<SCAT_B, 256, 0, stream>>>(ep0, cnt, rank);
    scan1_kernel<<<NB_SCAN, SCAN_B, 0, stream>>>(cnt, pre, bsum, dinv);
    scatter_kernel<<<N_SLICE, 256, 0, stream>>>(ep0, rank, pre, bsum, dinv, ep);
    // Layer 1: h1 = relu((A_norm x) W1 + b1)   [agg on 32-wide input]
    fused_layer32_kernel<<<FB, 256, 0, stream>>>(pre, bsum, ep, dinv, xb, W1, b1, H);
    // Layer 2: h2 = relu((A_norm h1) W2 + b2)
    fused_layer64_kernel<<<FB, 256, 0, stream>>>(pre, bsum, ep, dinv, H, W2, b2, G);
    // Heads: q = A_norm h2 ; mu = qWmu+bmu ; lv = qWlv+blv ; z = mu+exp(.5lv)eps
    fused_head_kernel<<<FB, 256, 0, stream>>>(pre, bsum, ep, dinv, G, Wmu, Wlv, bmu, blv, eps, out);
}

// Round 5
// 249.062 us; speedup vs baseline: 1.0073x; 1.0073x over previous
//
#include <hip/hip_runtime.h>
#include <math.h>

#define N_NODES 50000
#define N_EDGES 800000
#define IN_DIM 32
#define HIDDEN 64
#define Z_DIM 32
#define SCAN_B 256
#define NB_SCAN ((N_NODES + SCAN_B - 1) / SCAN_B)   // 196
#define N_XCD 8
#define NPX ((N_NODES + N_XCD - 1) / N_XCD)         // 6250 nodes per XCD range
#define SLICE 2048
#define N_SLICE ((N_EDGES + SLICE - 1) / SLICE)     // 391
#define SCAT_B (N_SLICE * N_XCD)                    // 3128 hist blocks
#define FB 1024                                     // 4096 waves for node kernels
#define CPAD 16                                     // cnt stride: 1 line/node

// bf16 (stored as ushort) <-> f32 helpers, RNE
__device__ __forceinline__ unsigned short f2bf(float f) {
    unsigned int u = __float_as_uint(f);
    u += 0x7fffu + ((u >> 16) & 1u);
    return (unsigned short)(u >> 16);
}

// wave-local edge dtype detect: int64 LE values < 2^31 have all-zero odd words.
__device__ __forceinline__ int detect64(const int* raw) {
    int lane = threadIdx.x & 63;
    int odd = raw[2 * lane + 1];
    unsigned long long b = __ballot(odd != 0);
    return (b == 0ULL) ? 1 : 0;
}

// 8 bf16 (packed in uint4) FMA into acc[8]
__device__ __forceinline__ void fma8(float w, uint4 f, float acc[8]) {
    acc[0] = fmaf(w, __uint_as_float(f.x << 16),         acc[0]);
    acc[1] = fmaf(w, __uint_as_float(f.x & 0xffff0000u), acc[1]);
    acc[2] = fmaf(w, __uint_as_float(f.y << 16),         acc[2]);
    acc[3] = fmaf(w, __uint_as_float(f.y & 0xffff0000u), acc[3]);
    acc[4] = fmaf(w, __uint_as_float(f.z << 16),         acc[4]);
    acc[5] = fmaf(w, __uint_as_float(f.z & 0xffff0000u), acc[5]);
    acc[6] = fmaf(w, __uint_as_float(f.w << 16),         acc[6]);
    acc[7] = fmaf(w, __uint_as_float(f.w & 0xffff0000u), acc[7]);
}
__device__ __forceinline__ void mul8(float w, uint4 f, float acc[8]) {
    acc[0] = w * __uint_as_float(f.x << 16);
    acc[1] = w * __uint_as_float(f.x & 0xffff0000u);
    acc[2] = w * __uint_as_float(f.y << 16);
    acc[3] = w * __uint_as_float(f.y & 0xffff0000u);
    acc[4] = w * __uint_as_float(f.z << 16);
    acc[5] = w * __uint_as_float(f.z & 0xffff0000u);
    acc[6] = w * __uint_as_float(f.w << 16);
    acc[7] = w * __uint_as_float(f.w & 0xffff0000u);
}

// ---------------------------------------------------------------------------
// prep_a: pure streaming. x->bf16 convert; edge compaction to ushort2 (node
// ids < 2^16); cnt zeroing folded in (saves the memset dispatch).
__global__ void prep_a_kernel(const float* __restrict__ x, unsigned short* __restrict__ xb,
                              const void* __restrict__ raw, ushort2* __restrict__ ep0,
                              int* __restrict__ cnt) {
    int is64 = detect64((const int*)raw);
    int i = blockIdx.x * 256 + threadIdx.x;
    if (i < N_NODES * IN_DIM) xb[i] = f2bf(x[i]);
    if (i < N_NODES * CPAD) cnt[i] = 0;
    if (i < N_EDGES) {
        int s, d;
        if (is64) {
            s = (int)((const long long*)raw)[i];
            d = (int)((const long long*)raw)[N_EDGES + i];
        } else {
            s = ((const int*)raw)[i];
            d = ((const int*)raw)[N_EDGES + i];
        }
        ep0[i] = make_ushort2((unsigned short)s, (unsigned short)d);
    }
}

// ---------------------------------------------------------------------------
// hist: XCD-partitioned degree count + per-edge rank capture. xcd = b%8 owns
// dst range -> atomics local to one XCD's L2. cnt padded 1 line/node. The
// atomic's return value is the edge's within-node rank.
__global__ __launch_bounds__(256) void hist_kernel(const ushort2* __restrict__ ep0,
                                                   int* __restrict__ cnt,
                                                   unsigned short* __restrict__ rank) {
    int xcd = blockIdx.x % N_XCD;
    int sl  = blockIdx.x / N_XCD;
    int lo  = xcd * NPX, hi = lo + NPX;
    int base = sl * SLICE;
#pragma unroll
    for (int j = 0; j < SLICE / 256; j++) {
        int e = base + j * 256 + threadIdx.x;
        if (e < N_EDGES) {
            int d = ep0[e].y;
            if (d >= lo && d < hi)
                rank[e] = (unsigned short)atomicAdd(&cnt[(size_t)d * CPAD], 1);
        }
    }
}

// ---------------------------------------------------------------------------
// scan1: block-local exclusive scan of cnt (padded) -> pre, block sums, dinv.
// Global offsets are applied by consumers via an LDS scan of bsum (no scan23).
__global__ void scan1_kernel(const int* __restrict__ cnt, int* __restrict__ pre,
                             int* __restrict__ bsum, float* __restrict__ dinv) {
    __shared__ int s[SCAN_B];
    int t = threadIdx.x;
    int g = blockIdx.x * SCAN_B + t;
    int v = (g < N_NODES) ? cnt[(size_t)g * CPAD] : 0;
    if (g < N_NODES) dinv[g] = rsqrtf((float)(v + 1));   // +1 self loop
    s[t] = v;
    __syncthreads();
    for (int o = 1; o < SCAN_B; o <<= 1) {
        int add = (t >= o) ? s[t - o] : 0;
        __syncthreads();
        s[t] += add;
        __syncthreads();
    }
    if (g < N_NODES) pre[g] = s[t] - v;
    if (t == SCAN_B - 1) bsum[blockIdx.x] = s[t];
}

// Block-start prologue: redundant LDS exclusive-scan of the 196 bsums.
// After this, rowptr(v) = pre[v] + sx[v>>8].
#define BSUM_SCAN_PROLOGUE(bsum, sb, sx)                                    \
    {                                                                       \
        int t_ = threadIdx.x;                                               \
        int bv_ = (t_ < NB_SCAN) ? bsum[t_] : 0;                            \
        sb[t_] = bv_;                                                       \
        __syncthreads();                                                    \
        for (int o_ = 1; o_ < 256; o_ <<= 1) {                              \
            int a_ = (t_ >= o_) ? sb[t_ - o_] : 0;                          \
            __syncthreads();                                                \
            sb[t_] += a_;                                                   \
            __syncthreads();                                                \
        }                                                                   \
        sx[t_] = sb[t_] - bv_;                                              \
        __syncthreads();                                                    \
    }

// ---------------------------------------------------------------------------
// Deterministic scatter: single pass, no atomics. Slot = rowptr[dst] + rank.
__global__ __launch_bounds__(256) void scatter_kernel(
        const ushort2* __restrict__ ep0, const unsigned short* __restrict__ rank,
        const int* __restrict__ pre, const int* __restrict__ bsum,
        const float* __restrict__ dinv, int2* __restrict__ ep) {
    __shared__ int sb[256];
    __shared__ int sx[256];
    BSUM_SCAN_PROLOGUE(bsum, sb, sx)
    int base = blockIdx.x * SLICE;
#pragma unroll
    for (int j = 0; j < SLICE / 256; j++) {
        int e = base + j * 256 + threadIdx.x;
        if (e < N_EDGES) {
            ushort2 sd = ep0[e];
            int d = sd.y;
            int p = pre[d] + sx[d >> 8] + (int)rank[e];
            int s = sd.x;
            ep[p] = make_int2(s, __float_as_int(dinv[s]));
        }
    }
}

// ---------------------------------------------------------------------------
// 64-wide aggregation. Edge batch staged once into the wave's LDS slot, then
// one ds_read_b64 per 8-edge group. Feature gathers are uint4: 8 lanes x 16B
// cover one 128B row -> 8 edges per load instruction. Masked slots hold
// (s=0,w=0): row-0 gather is an L1 broadcast hit, FMA contributes 0.
__device__ __forceinline__ void agg64(int e0, int e1, int2 pr,
                                      const int2* __restrict__ ep,
                                      const uint4* __restrict__ g4,
                                      int2* eb, int lane, int gsel, int c,
                                      float acc[8]) {
    for (int b0 = e0; b0 < e1; b0 += 64) {
        int cnt = e1 - b0; cnt = cnt > 64 ? 64 : cnt;        // uniform
        eb[lane] = pr;                                       // stage batch
        for (int j = 0; j < cnt; j += 16) {
            int2 ew0 = eb[j + gsel];                         // gsel in 0..7
            int2 ew1 = eb[j + 8 + gsel];
            uint4 f0 = g4[(size_t)ew0.x * 8 + c];
            uint4 f1 = g4[(size_t)ew1.x * 8 + c];
            fma8(__int_as_float(ew0.y), f0, acc);
            fma8(__int_as_float(ew1.y), f1, acc);
        }
        if (b0 + 64 < e1) {                                  // rare extra batch
            pr = make_int2(0, 0);
            int idx = b0 + 64 + lane;
            if (idx < e1) pr = ep[idx];
        }
    }
}

// 32-wide aggregation: 4 lanes x 16B cover one 64B row -> 16 edges per load.
__device__ __forceinline__ void agg32(int e0, int e1, int2 pr,
                                      const int2* __restrict__ ep,
                                      const uint4* __restrict__ x4,
                                      int2* eb, int lane, int gsel, int c,
                                      float acc[8]) {
    for (int b0 = e0; b0 < e1; b0 += 64) {
        int cnt = e1 - b0; cnt = cnt > 64 ? 64 : cnt;
        eb[lane] = pr;
        for (int j = 0; j < cnt; j += 32) {
            int2 ew0 = eb[j + gsel];                         // gsel in 0..15
            int2 ew1 = eb[j + 16 + gsel];
            uint4 f0 = x4[(size_t)ew0.x * 4 + c];
            uint4 f1 = x4[(size_t)ew1.x * 4 + c];
            fma8(__int_as_float(ew0.y), f0, acc);
            fma8(__int_as_float(ew1.y), f1, acc);
        }
        if (b0 + 64 < e1) {
            pr = make_int2(0, 0);
            int idx = b0 + 64 + lane;
            if (idx < e1) pr = ep[idx];
        }
    }
}

// ---------------------------------------------------------------------------
// Fused layer 1: q = normAgg(xb) [32-wide, f32], out = relu(q @ W1 + b1).
// NOTE: no min-occupancy clause -- wcol MUST stay register-resident (the
// (256,4) cap at ~128 VGPR made the allocator spill it; 64 scratch reloads
// per node per lane dominated the kernel).
__global__ __launch_bounds__(256) void fused_layer32_kernel(
        const int* __restrict__ pre, const int* __restrict__ bsum,
        const int2* __restrict__ ep, const float* __restrict__ dinv,
        const unsigned short* __restrict__ xb,
        const float* __restrict__ W1, const float* __restrict__ b1,
        unsigned short* __restrict__ out) {
    __shared__ int sb[256];
    __shared__ int sx[256];
    __shared__ int2 ebuf[4][64];
    __shared__ float sq[4][32];
    BSUM_SCAN_PROLOGUE(bsum, sb, sx)
    int lane = threadIdx.x & 63;
    int wav  = threadIdx.x >> 6;
    int gsel = lane >> 2;                                    // 16 groups
    int c    = lane & 3;                                     // 4 x uint4 = 64B row
    const uint4* x4 = (const uint4*)xb;
    int2* eb = &ebuf[wav][0];
    float wcol[IN_DIM];
#pragma unroll
    for (int k = 0; k < IN_DIM; k++) wcol[k] = W1[k * 64 + lane];
    float bb = b1[lane];
    int wid = __builtin_amdgcn_readfirstlane((int)((blockIdx.x * blockDim.x + threadIdx.x) >> 6));
    int nw  = (gridDim.x * blockDim.x) >> 6;
    int v = wid;
    if (v >= N_NODES) return;
    int e0 = pre[v] + sx[v >> 8];
    int e1 = (v + 1 < N_NODES) ? pre[v + 1] + sx[(v + 1) >> 8] : N_EDGES;
    float dv = dinv[v];
    uint4 hv = x4[(size_t)v * 4 + c];
    int2 pr = make_int2(0, 0);
    if (lane < e1 - e0) pr = ep[e0 + lane];                  // exec-masked load
    while (v < N_NODES) {
        int vn = v + nw;
        int e0n = 0, e1n = 0;
        float dvn = 0.0f;
        uint4 hvn = make_uint4(0, 0, 0, 0);
        int2 prn = make_int2(0, 0);
        if (vn < N_NODES) {                                  // prefetch next node
            e0n = pre[vn] + sx[vn >> 8];
            e1n = (vn + 1 < N_NODES) ? pre[vn + 1] + sx[(vn + 1) >> 8] : N_EDGES;
            dvn = dinv[vn];
            hvn = x4[(size_t)vn * 4 + c];
            if (lane < e1n - e0n) prn = ep[e0n + lane];
        }
        float sv = (gsel == 0) ? dv : 0.0f;                  // self term once
        float acc[8];
        mul8(sv, hv, acc);
        agg32(e0, e1, pr, ep, x4, eb, lane, gsel, c, acc);
#pragma unroll
        for (int i = 0; i < 8; i++) {
            acc[i] += __shfl_xor(acc[i], 4);
            acc[i] += __shfl_xor(acc[i], 8);
            acc[i] += __shfl_xor(acc[i], 16);
            acc[i] += __shfl_xor(acc[i], 32);
        }
        if (lane < 4) {
            float4* qd = (float4*)(&sq[wav][lane * 8]);
            qd[0] = make_float4(dv * acc[0], dv * acc[1], dv * acc[2], dv * acc[3]);
            qd[1] = make_float4(dv * acc[4], dv * acc[5], dv * acc[6], dv * acc[7]);
        }
        // dense apply: 4 independent FMA chains (was 1 serial chain of 32)
        float o0 = bb, o1 = 0.0f, o2 = 0.0f, o3 = 0.0f;
        const float4* q4 = (const float4*)(&sq[wav][0]);
#pragma unroll
        for (int k = 0; k < IN_DIM / 4; k++) {
            float4 tq = q4[k];
            o0 = fmaf(tq.x, wcol[4 * k + 0], o0);
            o1 = fmaf(tq.y, wcol[4 * k + 1], o1);
            o2 = fmaf(tq.z, wcol[4 * k + 2], o2);
            o3 = fmaf(tq.w, wcol[4 * k + 3], o3);
        }
        float o = (o0 + o1) + (o2 + o3);
        out[(size_t)v * 64 + lane] = f2bf(fmaxf(o, 0.0f));
        v = vn; e0 = e0n; e1 = e1n; dv = dvn; hv = hvn; pr = prn;
    }
}

// Fused layer 2: q = normAgg(g) [64-wide, f32], out = relu(q @ W + b).
__global__ __launch_bounds__(256) void fused_layer64_kernel(
        const int* __restrict__ pre, const int* __restrict__ bsum,
        const int2* __restrict__ ep, const float* __restrict__ dinv,
        const unsigned short* __restrict__ g,
        const float* __restrict__ W, const float* __restrict__ bias,
        unsigned short* __restrict__ out) {
    __shared__ int sb[256];
    __shared__ int sx[256];
    __shared__ int2 ebuf[4][64];
    __shared__ float sq[4][64];
    BSUM_SCAN_PROLOGUE(bsum, sb, sx)
    int lane = threadIdx.x & 63;
    int wav  = threadIdx.x >> 6;
    int gsel = lane >> 3;                                    // 8 groups
    int c    = lane & 7;                                     // 8 x uint4 = 128B row
    const uint4* g4 = (const uint4*)g;
    int2* eb = &ebuf[wav][0];
    float wcol[HIDDEN];
#pragma unroll
    for (int k = 0; k < HIDDEN; k++) wcol[k] = W[k * 64 + lane];
    float bb = bias[lane];
    int wid = __builtin_amdgcn_readfirstlane((int)((blockIdx.x * blockDim.x + threadIdx.x) >> 6));
    int nw  = (gridDim.x * blockDim.x) >> 6;
    int v = wid;
    if (v >= N_NODES) return;
    int e0 = pre[v] + sx[v >> 8];
    int e1 = (v + 1 < N_NODES) ? pre[v + 1] + sx[(v + 1) >> 8] : N_EDGES;
    float dv = dinv[v];
    uint4 hv = g4[(size_t)v * 8 + c];
    int2 pr = make_int2(0, 0);
    if (lane < e1 - e0) pr = ep[e0 + lane];
    while (v < N_NODES) {
        int vn = v + nw;
        int e0n = 0, e1n = 0;
        float dvn = 0.0f;
        uint4 hvn = make_uint4(0, 0, 0, 0);
        int2 prn = make_int2(0, 0);
        if (vn < N_NODES) {
            e0n = pre[vn] + sx[vn >> 8];
            e1n = (vn + 1 < N_NODES) ? pre[vn + 1] + sx[(vn + 1) >> 8] : N_EDGES;
            dvn = dinv[vn];
            hvn = g4[(size_t)vn * 8 + c];
            if (lane < e1n - e0n) prn = ep[e0n + lane];
        }
        float sv = (gsel == 0) ? dv : 0.0f;
        float acc[8];
        mul8(sv, hv, acc);
        agg64(e0, e1, pr, ep, g4, eb, lane, gsel, c, acc);
#pragma unroll
        for (int i = 0; i < 8; i++) {
            acc[i] += __shfl_xor(acc[i], 8);
            acc[i] += __shfl_xor(acc[i], 16);
            acc[i] += __shfl_xor(acc[i], 32);
        }
        if (lane < 8) {
            float4* qd = (float4*)(&sq[wav][lane * 8]);
            qd[0] = make_float4(dv * acc[0], dv * acc[1], dv * acc[2], dv * acc[3]);
            qd[1] = make_float4(dv * acc[4], dv * acc[5], dv * acc[6], dv * acc[7]);
        }
        float o0 = bb, o1 = 0.0f, o2 = 0.0f, o3 = 0.0f;
        const float4* q4 = (const float4*)(&sq[wav][0]);
#pragma unroll
        for (int k = 0; k < HIDDEN / 4; k++) {
            float4 tq = q4[k];
            o0 = fmaf(tq.x, wcol[4 * k + 0], o0);
            o1 = fmaf(tq.y, wcol[4 * k + 1], o1);
            o2 = fmaf(tq.z, wcol[4 * k + 2], o2);
            o3 = fmaf(tq.w, wcol[4 * k + 3], o3);
        }
        float o = (o0 + o1) + (o2 + o3);
        out[(size_t)v * 64 + lane] = f2bf(fmaxf(o, 0.0f));
        v = vn; e0 = e0n; e1 = e1n; dv = dvn; hv = hvn; pr = prn;
    }
}

// Fused heads: q = normAgg(h2); mu = q@Wmu+bmu (lanes<32), lv = q@Wlv+blv
// (lanes>=32); z = mu + exp(.5 lv) * eps. d_out = [z | mu | lv] fp32.
__global__ __launch_bounds__(256) void fused_head_kernel(
        const int* __restrict__ pre, const int* __restrict__ bsum,
        const int2* __restrict__ ep, const float* __restrict__ dinv,
        const unsigned short* __restrict__ g,
        const float* __restrict__ Wmu, const float* __restrict__ Wlv,
        const float* __restrict__ bmu, const float* __restrict__ blv,
        const float* __restrict__ eps, float* __restrict__ outz) {
    __shared__ int sb[256];
    __shared__ int sx[256];
    __shared__ int2 ebuf[4][64];
    __shared__ float sq[4][64];
    BSUM_SCAN_PROLOGUE(bsum, sb, sx)
    int lane = threadIdx.x & 63;
    int wav  = threadIdx.x >> 6;
    int gsel = lane >> 3;
    int c    = lane & 7;
    int f = lane & 31;
    bool hi = lane >= 32;
    const uint4* g4 = (const uint4*)g;
    int2* eb = &ebuf[wav][0];
    float wcol[HIDDEN];
#pragma unroll
    for (int k = 0; k < HIDDEN; k++)
        wcol[k] = hi ? Wlv[k * 32 + f] : Wmu[k * 32 + f];
    float bb = hi ? blv[f] : bmu[f];
    float* z  = outz;
    float* mu = outz + (size_t)N_NODES * Z_DIM;
    float* lv = outz + 2 * (size_t)N_NODES * Z_DIM;
    int wid = __builtin_amdgcn_readfirstlane((int)((blockIdx.x * blockDim.x + threadIdx.x) >> 6));
    int nw  = (gridDim.x * blockDim.x) >> 6;
    int v = wid;
    if (v >= N_NODES) return;
    int e0 = pre[v] + sx[v >> 8];
    int e1 = (v + 1 < N_NODES) ? pre[v + 1] + sx[(v + 1) >> 8] : N_EDGES;
    float dv = dinv[v];
    uint4 hv = g4[(size_t)v * 8 + c];
    int2 pr = make_int2(0, 0);
    if (lane < e1 - e0) pr = ep[e0 + lane];
    while (v < N_NODES) {
        int vn = v + nw;
        int e0n = 0, e1n = 0;
        float dvn = 0.0f;
        uint4 hvn = make_uint4(0, 0, 0, 0);
        int2 prn = make_int2(0, 0);
        if (vn < N_NODES) {
            e0n = pre[vn] + sx[vn >> 8];
            e1n = (vn + 1 < N_NODES) ? pre[vn + 1] + sx[(vn + 1) >> 8] : N_EDGES;
            dvn = dinv[vn];
            hvn = g4[(size_t)vn * 8 + c];
            if (lane < e1n - e0n) prn = ep[e0n + lane];
        }
        float sv = (gsel == 0) ? dv : 0.0f;
        float acc[8];
        mul8(sv, hv, acc);
        agg64(e0, e1, pr, ep, g4, eb, lane, gsel, c, acc);
#pragma unroll
        for (int i = 0; i < 8; i++) {
            acc[i] += __shfl_xor(acc[i], 8);
            acc[i] += __shfl_xor(acc[i], 16);
            acc[i] += __shfl_xor(acc[i], 32);
        }
        if (lane < 8) {
            float4* qd = (float4*)(&sq[wav][lane * 8]);
            qd[0] = make_float4(dv * acc[0], dv * acc[1], dv * acc[2], dv * acc[3]);
            qd[1] = make_float4(dv * acc[4], dv * acc[5], dv * acc[6], dv * acc[7]);
        }
        float m0 = bb, m1 = 0.0f, m2 = 0.0f, m3 = 0.0f;
        const float4* q4 = (const float4*)(&sq[wav][0]);
#pragma unroll
        for (int k = 0; k < HIDDEN / 4; k++) {
            float4 tq = q4[k];
            m0 = fmaf(tq.x, wcol[4 * k + 0], m0);
            m1 = fmaf(tq.y, wcol[4 * k + 1], m1);
            m2 = fmaf(tq.z, wcol[4 * k + 2], m2);
            m3 = fmaf(tq.w, wcol[4 * k + 3], m3);
        }
        float m = (m0 + m1) + (m2 + m3);
        float ev = eps[(size_t)v * Z_DIM + f];
        float t  = expf(0.5f * m) * ev;
        float tlo = __shfl(t, lane | 32);
        size_t o = (size_t)v * Z_DIM + f;
        if (!hi) { mu[o] = m; z[o] = m + tlo; }
        else     { lv[o] = m; }
        v = vn; e0 = e0n; e1 = e1n; dv = dvn; hv = hvn; pr = prn;
    }
}

// ---------------------------------------------------------------------------
extern "C" void kernel_launch(void* const* d_in, const int* in_sizes, int n_in,
                              void* d_out, int out_size, void* d_ws, size_t ws_size,
                              hipStream_t stream) {
    const float* x   = (const float*)d_in[0];
    const void*  ei  = d_in[1];
    const float* W1  = (const float*)d_in[2];
    const float* b1  = (const float*)d_in[3];
    const float* W2  = (const float*)d_in[4];
    const float* b2  = (const float*)d_in[5];
    const float* Wmu = (const float*)d_in[6];
    const float* bmu = (const float*)d_in[7];
    const float* Wlv = (const float*)d_in[8];
    const float* blv = (const float*)d_in[9];
    const float* eps = (const float*)d_in[10];
    float* out = (float*)d_out;
    (void)in_sizes; (void)n_in; (void)out_size; (void)ws_size;

    char* ws = (char*)d_ws;
    size_t off = 0;
    auto alloc = [&](size_t bytes) -> void* {
        void* p = ws + off;
        off += (bytes + 255) & ~(size_t)255;
        return p;
    };
    int2*           ep     = (int2*)alloc(sizeof(int2) * N_EDGES);       // 6.4 MB
    ushort2*        ep0    = (ushort2*)alloc(sizeof(ushort2) * N_EDGES); // 3.2 MB
    unsigned short* rank   = (unsigned short*)alloc(sizeof(short) * N_EDGES);  // 1.6 MB
    int*            pre    = (int*)alloc(sizeof(int) * (N_NODES + 1));
    int*            cnt    = (int*)alloc(sizeof(int) * (size_t)N_NODES * CPAD); // 3.2 MB
    float*          dinv   = (float*)alloc(sizeof(float) * N_NODES);
    int*            bsum   = (int*)alloc(sizeof(int) * 256);
    unsigned short* xb     = (unsigned short*)alloc(sizeof(short) * (size_t)N_NODES * IN_DIM);  // 3.2 MB
    unsigned short* G      = (unsigned short*)alloc(sizeof(short) * (size_t)N_NODES * HIDDEN);  // 6.4 MB
    unsigned short* H      = (unsigned short*)alloc(sizeof(short) * (size_t)N_NODES * HIDDEN);  // 6.4 MB

    prep_a_kernel<<<(N_NODES * IN_DIM + 255) / 256, 256, 0, stream>>>(x, xb, ei, ep0, cnt);
    hist_kernel<<<SCAT_B, 256, 0, stream>>>(ep0, cnt, rank);
    scan1_kernel<<<NB_SCAN, SCAN_B, 0, stream>>>(cnt, pre, bsum, dinv);
    scatter_kernel<<<N_SLICE, 256, 0, stream>>>(ep0, rank, pre, bsum, dinv, ep);
    // Layer 1: h1 = relu((A_norm x) W1 + b1)   [agg on 32-wide input]
    fused_layer32_kernel<<<FB, 256, 0, stream>>>(pre, bsum, ep, dinv, xb, W1, b1, H);
    // Layer 2: h2 = relu((A_norm h1) W2 + b2)
    fused_layer64_kernel<<<FB, 256, 0, stream>>>(pre, bsum, ep, dinv, H, W2, b2, G);
    // Heads: q = A_norm h2 ; mu = qWmu+bmu ; lv = qWlv+blv ; z = mu+exp(.5lv)eps
    fused_head_kernel<<<FB, 256, 0, stream>>>(pre, bsum, ep, dinv, G, Wmu, Wlv, bmu, blv, eps, out);
}